// Round 4
// baseline (302.399 us; speedup 1.0000x reference)
//
#include <hip/hip_runtime.h>

// SSIM over 11x11 gaussian-weighted patches — float4-coalesced LDS staging.
// pred: [4, 2048, 16, 121, 3] f32   gt: [2048, 16, 121, 3] f32
// out:  [4, 2048, 16] f32
//
// Block = 256 threads = 16 outputs. The block's pred/gt spans are contiguous
// 23232-B 16-aligned regions -> staged to LDS as 1452 float4 each
// (global_load_dwordx4 + ds_write_b128, max HBM transaction efficiency).
// Compute: 16 lanes/output read pixels from LDS, 15 stats reduced via
// shfl_xor (masks 1/2/4/8 stay inside the 16-lane group).

static constexpr int N_OUT   = 4 * 2048 * 16;   // 131072
static constexpr int NP_MASK = 2048 * 16 - 1;   // 32767 (N*n_p is pow2)
static constexpr int OPB     = 16;              // outputs per block
static constexpr int FLT_BLK = OPB * 363;       // 5808 floats per array
static constexpr int VEC_BLK = FLT_BLK / 4;     // 1452 float4 per array

__device__ __constant__ float G11[11] = {
    0.00102838f, 0.00759875f, 0.03600077f, 0.10936070f, 0.21300555f,
    0.26601173f,
    0.21300555f, 0.10936070f, 0.03600077f, 0.00759875f, 0.00102838f
};

__device__ __forceinline__ float red16(float v) {
    v += __shfl_xor(v, 1);
    v += __shfl_xor(v, 2);
    v += __shfl_xor(v, 4);
    v += __shfl_xor(v, 8);
    return v;
}

__global__ __launch_bounds__(256) void ssim_kernel(
    const float* __restrict__ pred, const float* __restrict__ gt,
    float* __restrict__ out)
{
    __shared__ float4 predS4[VEC_BLK];   // 23232 B
    __shared__ float4 gtS4  [VEC_BLK];   // 23232 B
    __shared__ float  W[128];            // 2D gaussian weights, zero-padded

    const int t = threadIdx.x;
    if (t < 128) {
        float w = 0.f;
        if (t < 121) {
            const int r = t / 11;
            const int c = t - r * 11;
            w = G11[r] * G11[c];
        }
        W[t] = w;
    }

    // ---- stage: perfectly coalesced float4 copies ----
    const float4* p4 = (const float4*)(pred + (size_t)blockIdx.x * FLT_BLK);
    const float4* g4 = (const float4*)(gt +
                        (size_t)((blockIdx.x * OPB) & NP_MASK) * 363);
    #pragma unroll
    for (int r = 0; r < 6; ++r) {
        const int idx = t + r * 256;
        if (idx < VEC_BLK) {
            predS4[idx] = p4[idx];
            gtS4  [idx] = g4[idx];
        }
    }
    __syncthreads();

    // ---- compute: 16 lanes per output, pixel-per-lane, from LDS ----
    const int lane  = t & 15;
    const int group = t >> 4;                      // 0..15
    const int o     = blockIdx.x * OPB + group;
    const float* p = (const float*)predS4 + group * 363;
    const float* g = (const float*)gtS4   + group * 363;

    float mu1[3] = {0.f, 0.f, 0.f};
    float mu2[3] = {0.f, 0.f, 0.f};
    float s1 [3] = {0.f, 0.f, 0.f};
    float s2 [3] = {0.f, 0.f, 0.f};
    float s12[3] = {0.f, 0.f, 0.f};

    #pragma unroll
    for (int rnd = 0; rnd < 8; ++rnd) {
        const int pix = lane + rnd * 16;               // 0..127
        const float w = W[pix];                        // 0 for pix >= 121
        const int pc  = (pix < 121 ? pix : 120) * 3;   // clamp: in-bounds
        const float pv[3] = {p[pc], p[pc + 1], p[pc + 2]};
        const float gv[3] = {g[pc], g[pc + 1], g[pc + 2]};
        #pragma unroll
        for (int c = 0; c < 3; ++c) {
            const float tp = w * pv[c];
            const float tg = w * gv[c];
            mu1[c] += tp;
            mu2[c] += tg;
            s1 [c] = fmaf(tp, pv[c], s1 [c]);
            s2 [c] = fmaf(tg, gv[c], s2 [c]);
            s12[c] = fmaf(tp, gv[c], s12[c]);
        }
    }

    #pragma unroll
    for (int c = 0; c < 3; ++c) {
        mu1[c] = red16(mu1[c]);
        mu2[c] = red16(mu2[c]);
        s1 [c] = red16(s1 [c]);
        s2 [c] = red16(s2 [c]);
        s12[c] = red16(s12[c]);
    }

    if (lane == 0) {
        const float C1 = 1e-4f;   // 0.01^2
        const float C2 = 9e-4f;   // 0.03^2
        float acc = 0.f;
        #pragma unroll
        for (int c = 0; c < 3; ++c) {
            const float m1 = mu1[c], m2 = mu2[c];
            const float m1sq = m1 * m1, m2sq = m2 * m2, m12 = m1 * m2;
            const float sig1 = s1[c]  - m1sq;
            const float sig2 = s2[c]  - m2sq;
            const float sg12 = s12[c] - m12;
            const float num = (2.f * m12 + C1) * (2.f * sg12 + C2);
            const float den = (m1sq + m2sq + C1) * (sig1 + sig2 + C2);
            acc += num / den;
        }
        out[o] = acc * (1.f / 3.f);
    }
}

extern "C" void kernel_launch(void* const* d_in, const int* in_sizes, int n_in,
                              void* d_out, int out_size, void* d_ws, size_t ws_size,
                              hipStream_t stream) {
    const float* pred = (const float*)d_in[0];
    const float* gt   = (const float*)d_in[1];
    float* out        = (float*)d_out;
    ssim_kernel<<<N_OUT / OPB, 256, 0, stream>>>(pred, gt, out);  // 8192 blocks
}

// Round 5
// 290.407 us; speedup vs baseline: 1.0413x; 1.0413x over previous
//
#include <hip/hip_runtime.h>

// SSIM over 11x11 gaussian-weighted patches.
// pred: [4, 2048, 16, 121, 3] f32   gt: [2048, 16, 121, 3] f32
// out:  [4, 2048, 16] f32
//
// R5: stage ONLY pred to LDS (float4-coalesced, 23 KB -> no LDS occupancy
// cap); gt (47 MB unique, 4x reuse -> L2/L3-resident) is loaded straight
// into registers BEFORE the staging barrier so its latency hides behind
// the pred staging. Compute: 16 lanes/output, pixel-per-lane, pred from
// LDS, gt from registers; 15 stats reduced via shfl_xor within 16-lane
// groups (masks 1/2/4/8 never cross the group boundary).

static constexpr int N_OUT   = 4 * 2048 * 16;   // 131072
static constexpr int NP_MASK = 2048 * 16 - 1;   // 32767 (N*n_p is pow2)
static constexpr int OPB     = 16;              // outputs per block
static constexpr int FLT_BLK = OPB * 363;       // 5808 floats of pred
static constexpr int VEC_BLK = FLT_BLK / 4;     // 1452 float4 of pred

__device__ __constant__ float G11[11] = {
    0.00102838f, 0.00759875f, 0.03600077f, 0.10936070f, 0.21300555f,
    0.26601173f,
    0.21300555f, 0.10936070f, 0.03600077f, 0.00759875f, 0.00102838f
};

__device__ __forceinline__ float red16(float v) {
    v += __shfl_xor(v, 1);
    v += __shfl_xor(v, 2);
    v += __shfl_xor(v, 4);
    v += __shfl_xor(v, 8);
    return v;
}

__global__ __launch_bounds__(256, 4) void ssim_kernel(
    const float* __restrict__ pred, const float* __restrict__ gt,
    float* __restrict__ out)
{
    __shared__ float4 predS4[VEC_BLK];   // 23232 B (pred only)
    __shared__ float  W[128];            // 2D gaussian weights, zero-padded

    const int t     = threadIdx.x;
    const int lane  = t & 15;
    const int group = t >> 4;                      // 0..15
    const int o     = blockIdx.x * OPB + group;    // output index

    // ---- gt -> registers, issued FIRST (latency hides behind staging) ----
    const float* g = gt + (size_t)(o & NP_MASK) * 363;
    float gv[8][3];
    #pragma unroll
    for (int rnd = 0; rnd < 8; ++rnd) {
        const int pix = lane + rnd * 16;               // 0..127
        const int pc  = (pix < 121 ? pix : 120) * 3;   // clamp: in-bounds
        gv[rnd][0] = g[pc];
        gv[rnd][1] = g[pc + 1];
        gv[rnd][2] = g[pc + 2];
    }

    // ---- weight table ----
    if (t < 128) {
        float w = 0.f;
        if (t < 121) {
            const int r = t / 11;
            const int c = t - r * 11;
            w = G11[r] * G11[c];
        }
        W[t] = w;
    }

    // ---- stage pred: perfectly coalesced float4 copies ----
    const float4* p4 = (const float4*)(pred + (size_t)blockIdx.x * FLT_BLK);
    #pragma unroll
    for (int r = 0; r < 6; ++r) {
        const int idx = t + r * 256;
        if (idx < VEC_BLK) predS4[idx] = p4[idx];
    }
    __syncthreads();

    // ---- compute: 16 lanes per output, pixel-per-lane ----
    const float* p = (const float*)predS4 + group * 363;

    float mu1[3] = {0.f, 0.f, 0.f};
    float mu2[3] = {0.f, 0.f, 0.f};
    float s1 [3] = {0.f, 0.f, 0.f};
    float s2 [3] = {0.f, 0.f, 0.f};
    float s12[3] = {0.f, 0.f, 0.f};

    #pragma unroll
    for (int rnd = 0; rnd < 8; ++rnd) {
        const int pix = lane + rnd * 16;               // 0..127
        const float w = W[pix];                        // 0 for pix >= 121
        const int pc  = (pix < 121 ? pix : 120) * 3;   // clamp: in-bounds
        const float pv[3] = {p[pc], p[pc + 1], p[pc + 2]};
        #pragma unroll
        for (int c = 0; c < 3; ++c) {
            const float pvc = pv[c];
            const float gvc = gv[rnd][c];
            const float tp = w * pvc;
            const float tg = w * gvc;
            mu1[c] += tp;
            mu2[c] += tg;
            s1 [c] = fmaf(tp, pvc, s1 [c]);
            s2 [c] = fmaf(tg, gvc, s2 [c]);
            s12[c] = fmaf(tp, gvc, s12[c]);
        }
    }

    // reduce the 15 stats across the 16-lane group
    #pragma unroll
    for (int c = 0; c < 3; ++c) {
        mu1[c] = red16(mu1[c]);
        mu2[c] = red16(mu2[c]);
        s1 [c] = red16(s1 [c]);
        s2 [c] = red16(s2 [c]);
        s12[c] = red16(s12[c]);
    }

    if (lane == 0) {
        const float C1 = 1e-4f;   // 0.01^2
        const float C2 = 9e-4f;   // 0.03^2
        float acc = 0.f;
        #pragma unroll
        for (int c = 0; c < 3; ++c) {
            const float m1 = mu1[c], m2 = mu2[c];
            const float m1sq = m1 * m1, m2sq = m2 * m2, m12 = m1 * m2;
            const float sig1 = s1[c]  - m1sq;
            const float sig2 = s2[c]  - m2sq;
            const float sg12 = s12[c] - m12;
            const float num = (2.f * m12 + C1) * (2.f * sg12 + C2);
            const float den = (m1sq + m2sq + C1) * (sig1 + sig2 + C2);
            acc += num / den;
        }
        out[o] = acc * (1.f / 3.f);
    }
}

extern "C" void kernel_launch(void* const* d_in, const int* in_sizes, int n_in,
                              void* d_out, int out_size, void* d_ws, size_t ws_size,
                              hipStream_t stream) {
    const float* pred = (const float*)d_in[0];
    const float* gt   = (const float*)d_in[1];
    float* out        = (float*)d_out;
    ssim_kernel<<<N_OUT / OPB, 256, 0, stream>>>(pred, gt, out);  // 8192 blocks
}